// Round 15
// baseline (467.500 us; speedup 1.0000x reference)
//
#include <hip/hip_runtime.h>
#include <math.h>

#define BATCH 64
#define WW 320
#define HWTOT 76800
#define HW4 19200
#define NJTRB 512       // jtr blocks, 8 per batch
#define JSL4 2400       // float4s per jtr block (contiguous)
#define NCONVB 512      // fused conv blocks: 64 batches x 8 quadrants (2x4 of 30x40)
#define KS 64
#define NSLICE 300

// LDS layout (floats): sR[66][47] | sH1[32][22][8] | sW1[72] | sB1[8]
#define SR_OFF 0
#define SR_LD 47
#define SH1_OFF (66 * 47)
#define SW1_OFF (SH1_OFF + 32 * 22 * 8)
#define SB1_OFF (SW1_OFF + 72)
#define SMEM_FLOATS (SB1_OFF + 8)   // 8814 -> 35,256 B -> 4 blocks/CU

// ================= K1: jtr partials (blocks<NJTRB) + fused conv1+conv2 ================
__global__ __launch_bounds__(256) void k_front(
    const float* __restrict__ Jt, const float* __restrict__ wgt,
    const float* __restrict__ Rin, const float* __restrict__ c1w,
    const float* __restrict__ c1b, const float* __restrict__ c2w,
    const float* __restrict__ c2b, float* __restrict__ part,
    float* __restrict__ h2) {
  __shared__ float smem[SMEM_FLOATS];
  int tid = threadIdx.x;
  if (blockIdx.x < NJTRB) {
    // ---- jtr: 6-row dot over 2400 contiguous float4s ----
    int b = blockIdx.x >> 3, s = blockIdx.x & 7;
    const float4* w4 = (const float4*)(wgt + (size_t)b * HWTOT);
    const float4* r4 = (const float4*)(Rin + (size_t)b * HWTOT);
    const float4* j4 = (const float4*)(Jt + (size_t)b * 6 * HWTOT);
    int base = s * JSL4;
    float acc[6] = {0.f, 0.f, 0.f, 0.f, 0.f, 0.f};
#pragma unroll 3
    for (int k = 0; k < 9; ++k) {
      int t = base + k * 256 + tid;
      float4 wv = w4[t], rv = r4[t];
      float4 p;
      p.x = wv.x * rv.x; p.y = wv.y * rv.y; p.z = wv.z * rv.z; p.w = wv.w * rv.w;
#pragma unroll
      for (int i = 0; i < 6; ++i) {
        float4 jv = j4[i * HW4 + t];
        acc[i] += jv.x * p.x + jv.y * p.y + jv.z * p.z + jv.w * p.w;
      }
    }
    if (tid < 96) {
      int t = base + 2304 + tid;
      float4 wv = w4[t], rv = r4[t];
      float4 p;
      p.x = wv.x * rv.x; p.y = wv.y * rv.y; p.z = wv.z * rv.z; p.w = wv.w * rv.w;
#pragma unroll
      for (int i = 0; i < 6; ++i) {
        float4 jv = j4[i * HW4 + t];
        acc[i] += jv.x * p.x + jv.y * p.y + jv.z * p.z + jv.w * p.w;
      }
    }
#pragma unroll
    for (int i = 0; i < 6; ++i) {
      float v = acc[i];
      for (int off = 32; off; off >>= 1) v += __shfl_down(v, off, 64);
      acc[i] = v;
    }
    float* sred = smem;
    int lane = tid & 63, wid = tid >> 6;
    if (lane == 0) {
#pragma unroll
      for (int i = 0; i < 6; ++i) sred[wid * 6 + i] = acc[i];
    }
    __syncthreads();
    if (tid < 6) {
      part[blockIdx.x * 6 + tid] =
          sred[0 + tid] + sred[6 + tid] + sred[12 + tid] + sred[18 + tid];
    }
    return;
  }
  // ---- fused conv: one (batch, quadrant) -> h2 tile 15x10 x 16oc ----
  int cb = blockIdx.x - NJTRB;       // 0..511
  int b = cb >> 3, q = cb & 7;
  int qy = q >> 2, qx = q & 3;       // quadrant: rows 15*qy.., cols 10*qx..
  float* sR = smem + SR_OFF;         // [66][47] pooled-R tile (zero-padded)
  float* sH1 = smem + SH1_OFF;       // [32][22][8] conv1 output tile
  float* sW1 = smem + SW1_OFF;       // [tap][oc]
  float* sB1 = smem + SB1_OFF;
  if (tid < 72) sW1[tid] = c1w[(tid & 7) * 9 + (tid >> 3)];
  if (tid < 8) sB1[tid] = c1b[tid];
  // stage pooled-R region: rows [60qy-3, +66), cols [40qx-3, +46) of 120x160
  const float* src = Rin + (size_t)b * HWTOT;
  for (int idx = tid; idx < 66 * 46; idx += 256) {
    int row = idx / 46, col = idx % 46;
    int py = 60 * qy - 3 + row, px = 40 * qx - 3 + col;
    float v = 0.f;
    if (py >= 0 && py < 120 && px >= 0 && px < 160) {
      const float2* r0 = (const float2*)(src + (size_t)(2 * py) * WW);
      const float2* r1 = (const float2*)(src + (size_t)(2 * py + 1) * WW);
      float2 a = r0[px], bb = r1[px];
      v = fmaxf(fmaxf(a.x, a.y), fmaxf(bb.x, bb.y));
    }
    sR[row * SR_LD + col] = v;
  }
  __syncthreads();
  // conv1(1->8)+relu+pool into sH1: h1 rows [30qy-1,+32), cols [20qx-1,+22)
  for (int idx = tid; idx < 32 * 22; idx += 256) {
    int r = idx / 22, c = idx % 22;
    int hr = 30 * qy - 1 + r, hc = 20 * qx - 1 + c;
    float v[8] = {0.f, 0.f, 0.f, 0.f, 0.f, 0.f, 0.f, 0.f};
    if (hr >= 0 && hr < 60 && hc >= 0 && hc < 80) {
      float wnd[4][4];
#pragma unroll
      for (int i = 0; i < 4; ++i)
#pragma unroll
        for (int j = 0; j < 4; ++j) wnd[i][j] = sR[(2 * r + i) * SR_LD + (2 * c + j)];
#pragma unroll
      for (int o = 0; o < 8; ++o) {
        float p00 = 0.f, p01 = 0.f, p10 = 0.f, p11 = 0.f;
#pragma unroll
        for (int tap = 0; tap < 9; ++tap) {
          int ky = tap / 3, kx = tap % 3;
          float w = sW1[tap * 8 + o];
          p00 += w * wnd[ky][kx];
          p01 += w * wnd[ky][kx + 1];
          p10 += w * wnd[ky + 1][kx];
          p11 += w * wnd[ky + 1][kx + 1];
        }
        float m = fmaxf(fmaxf(p00, p01), fmaxf(p10, p11)) + sB1[o];
        v[o] = fmaxf(m, 0.f);
      }
    }
    float4* d = (float4*)&sH1[(r * 22 + c) * 8];
    d[0] = make_float4(v[0], v[1], v[2], v[3]);
    d[1] = make_float4(v[4], v[5], v[6], v[7]);
  }
  __syncthreads();
  // conv2(8->16)+relu+pool -> h2. Work item = (ocHalf = tid>>7 [wave-uniform], cell)
  int oh = tid >> 7;                       // 0: oc 0-7, 1: oc 8-15
  const float* wbase = c2w + oh * 8 * 72;  // wave-uniform -> scalar loads
#pragma unroll 1
  for (int cell = (tid & 127); cell < 150; cell += 128) {
    int r2l = cell / 10, c2l = cell % 10;
    float acc[8][4];
#pragma unroll
    for (int o = 0; o < 8; ++o)
#pragma unroll
      for (int p = 0; p < 4; ++p) acc[o][p] = 0.f;
#pragma unroll
    for (int wy = 0; wy < 4; ++wy) {
#pragma unroll
      for (int wx = 0; wx < 4; ++wx) {
        const float* cp = &sH1[((2 * r2l + wy) * 22 + (2 * c2l + wx)) * 8];
        float4 c0 = *(const float4*)cp;
        float4 c1 = *(const float4*)(cp + 4);
        float cell8[8] = {c0.x, c0.y, c0.z, c0.w, c1.x, c1.y, c1.z, c1.w};
#pragma unroll
        for (int dy = 0; dy < 2; ++dy) {
          int ky = wy - dy;
          if (ky < 0 || ky > 2) continue;
#pragma unroll
          for (int dx = 0; dx < 2; ++dx) {
            int kx = wx - dx;
            if (kx < 0 || kx > 2) continue;
            int tap = ky * 3 + kx;
#pragma unroll
            for (int o = 0; o < 8; ++o) {
              const float* wrow = wbase + o * 72 + tap;
              float a = acc[o][dy * 2 + dx];
#pragma unroll
              for (int ic = 0; ic < 8; ++ic) a += cell8[ic] * wrow[ic * 9];
              acc[o][dy * 2 + dx] = a;
            }
          }
        }
      }
    }
    int r2 = 15 * qy + r2l, c2 = 10 * qx + c2l;
#pragma unroll
    for (int o = 0; o < 8; ++o) {
      int oc = oh * 8 + o;
      float m = fmaxf(fmaxf(acc[o][0], acc[o][1]), fmaxf(acc[o][2], acc[o][3])) + c2b[oc];
      h2[(((size_t)b * 16 + oc) * 30 + r2) * 40 + c2] = fmaxf(m, 0.f);
    }
  }
}

// ================= K2: fc1 partial GEMM, KS=64, 300 slices, transposed out =============
__global__ __launch_bounds__(256) void k_fc1_part(
    const float* __restrict__ h2, const float* __restrict__ f1w,
    float* __restrict__ fcpart) {
  __shared__ __align__(16) float sH[KS * 68];
  __shared__ __align__(16) float sWt[KS * 68];
  int sl = blockIdx.x, k0 = sl * KS;
  int tid = threadIdx.x;
  for (int idx = tid; idx < 64 * KS; idx += 256) {
    int b = idx >> 6, kk = idx & 63;
    sH[kk * 68 + b] = h2[(size_t)b * 19200 + k0 + kk];
    sWt[kk * 68 + b] = f1w[(size_t)b * 19200 + k0 + kk];
  }
  __syncthreads();
  int bq = tid & 15, jq = tid >> 4;
  int b0 = bq * 4, j0 = jq * 4;
  float acc[4][4];
#pragma unroll
  for (int i = 0; i < 4; ++i)
#pragma unroll
    for (int j = 0; j < 4; ++j) acc[i][j] = 0.f;
  for (int kk = 0; kk < KS; ++kk) {
    float4 hv = *(const float4*)&sH[kk * 68 + b0];
    float4 wv = *(const float4*)&sWt[kk * 68 + j0];
    float hb[4] = {hv.x, hv.y, hv.z, hv.w};
    float wb[4] = {wv.x, wv.y, wv.z, wv.w};
#pragma unroll
    for (int i = 0; i < 4; ++i)
#pragma unroll
      for (int j = 0; j < 4; ++j) acc[i][j] += hb[i] * wb[j];
  }
#pragma unroll
  for (int i = 0; i < 4; ++i)
#pragma unroll
    for (int j = 0; j < 4; ++j)
      fcpart[(size_t)(b0 + i) * 19200 + sl * 64 + (j0 + j)] = acc[i][j];
}

// ================= K3: per-batch fc1-reduce + head + jtr-reduce + solve ================
__global__ __launch_bounds__(256) void k_final(
    const float* __restrict__ fcpart, const float* __restrict__ f1b,
    const float* __restrict__ f2w, const float* __restrict__ f2b,
    const float* __restrict__ consts, const float* __restrict__ part,
    const float* __restrict__ JtJ, const float* __restrict__ poseR,
    const float* __restrict__ poseT, float* __restrict__ out) {
  __shared__ __align__(16) float sred[16 * 64];
  __shared__ float fc1v[64];
  __shared__ float sf2w[384];
  __shared__ float sf2b[8];
  __shared__ float sconst[36];
  __shared__ float lg[6];
  __shared__ float lamv[6];
  __shared__ float jtrv[6];
  int b = blockIdx.x, tid = threadIdx.x;
  for (int i = tid; i < 384; i += 256) sf2w[i] = f2w[i];
  if (tid < 6) sf2b[tid] = f2b[tid];
  if (tid < 36) sconst[tid] = consts[tid];
  {
    const float4* fp4 = (const float4*)(fcpart + (size_t)b * 19200);
    int sg = tid >> 4, j4 = tid & 15;
    float4 a = make_float4(0.f, 0.f, 0.f, 0.f);
    for (int s = sg; s < NSLICE; s += 16) {
      float4 v = fp4[s * 16 + j4];
      a.x += v.x; a.y += v.y; a.z += v.z; a.w += v.w;
    }
    ((float4*)sred)[sg * 16 + j4] = a;
  }
  if (tid >= 64 && tid < 70) {
    int i = tid - 64;
    float v = 0.f;
    for (int s = 0; s < 8; ++s) v += part[(b * 8 + s) * 6 + i];
    jtrv[i] = v;
  }
  __syncthreads();
  if (tid < 64) {
    float v = 0.f;
#pragma unroll
    for (int sg = 0; sg < 16; ++sg) v += sred[sg * 64 + tid];
    fc1v[tid] = fmaxf(v + f1b[tid], 0.f);
  }
  __syncthreads();
  if (tid < 6) {
    float v = sf2b[tid];
#pragma unroll
    for (int k = 0; k < 64; ++k) v += fc1v[k] * sf2w[tid * 64 + k];
    lg[tid] = v;
  }
  __syncthreads();
  if (tid < 6) {
    float m = lg[0];
#pragma unroll
    for (int i = 1; i < 6; ++i) m = fmaxf(m, lg[i]);
    float e[6], ssum = 0.f;
#pragma unroll
    for (int i = 0; i < 6; ++i) { e[i] = expf(lg[i] - m); ssum += e[i]; }
    float inv = 1.f / ssum;
    float wc = 0.f;
#pragma unroll
    for (int i = 0; i < 6; ++i) wc += (e[i] * inv) * sconst[i * 6 + tid];
    float sg = 1.f / (1.f + expf(-wc));
    lamv[tid] = expf((-6.f + sg) * 2.302585092994046f);
  }
  __syncthreads();
  if (tid == 0) {
    float Hm[6][6];
    const float* srcH = JtJ + b * 36;
    float tr = 0.f;
#pragma unroll
    for (int i = 0; i < 6; ++i) {
#pragma unroll
      for (int jj = 0; jj < 6; ++jj) Hm[i][jj] = srcH[i * 6 + jj];
      tr += srcH[i * 6 + i];
    }
    float rhs[6];
#pragma unroll
    for (int i = 0; i < 6; ++i) {
      rhs[i] = jtrv[i];
      Hm[i][i] += lamv[i] + 1e-6f * tr + 1e-6f;
    }
    float L[6][6];
#pragma unroll
    for (int i = 0; i < 6; ++i) {
#pragma unroll
      for (int jj = 0; jj < 6; ++jj) {
        if (jj > i) continue;
        float s = Hm[i][jj];
#pragma unroll
        for (int k = 0; k < 6; ++k)
          if (k < jj) s -= L[i][k] * L[jj][k];
        if (i == jj) L[i][jj] = sqrtf(fmaxf(s, 1e-30f));
        else L[i][jj] = s / L[jj][jj];
      }
    }
    float yv[6];
#pragma unroll
    for (int i = 0; i < 6; ++i) {
      float s = rhs[i];
#pragma unroll
      for (int k = 0; k < 6; ++k)
        if (k < i) s -= L[i][k] * yv[k];
      yv[i] = s / L[i][i];
    }
    float xi[6];
#pragma unroll
    for (int ii = 5; ii >= 0; --ii) {
      float s = yv[ii];
#pragma unroll
      for (int k = 0; k < 6; ++k)
        if (k > ii) s -= L[k][ii] * xi[k];
      xi[ii] = s / L[ii][ii];
    }
    float wx = -xi[0], wy = -xi[1], wz = -xi[2];
    float th = fmaxf(sqrtf(wx * wx + wy * wy + wz * wz), 1e-12f);
    float ux = wx / th, uy = wy / th, uz = wz / th;
    float s = sinf(th), c1 = 1.f - cosf(th);
    float Rd[3][3];
    Rd[0][0] = 1.f + c1 * (ux * ux - 1.f);
    Rd[0][1] = -s * uz + c1 * (ux * uy);
    Rd[0][2] = s * uy + c1 * (ux * uz);
    Rd[1][0] = s * uz + c1 * (uy * ux);
    Rd[1][1] = 1.f + c1 * (uy * uy - 1.f);
    Rd[1][2] = -s * ux + c1 * (uy * uz);
    Rd[2][0] = -s * uy + c1 * (uz * ux);
    Rd[2][1] = s * ux + c1 * (uz * uy);
    Rd[2][2] = 1.f + c1 * (uz * uz - 1.f);
    float dt[3];
#pragma unroll
    for (int r = 0; r < 3; ++r)
      dt[r] = -(Rd[r][0] * xi[3] + Rd[r][1] * xi[4] + Rd[r][2] * xi[5]);
    const float* pR = poseR + b * 9;
    const float* pt = poseT + b * 3;
#pragma unroll
    for (int r = 0; r < 3; ++r) {
#pragma unroll
      for (int cc = 0; cc < 3; ++cc) {
        out[b * 12 + r * 4 + cc] =
            pR[r * 3 + 0] * Rd[0][cc] + pR[r * 3 + 1] * Rd[1][cc] + pR[r * 3 + 2] * Rd[2][cc];
      }
      out[b * 12 + r * 4 + 3] =
          pR[r * 3 + 0] * dt[0] + pR[r * 3 + 1] * dt[1] + pR[r * 3 + 2] * dt[2] + pt[r];
    }
  }
}

extern "C" void kernel_launch(void* const* d_in, const int* in_sizes, int n_in,
                              void* d_out, int out_size, void* d_ws, size_t ws_size,
                              hipStream_t stream) {
  const float* JtJ = (const float*)d_in[0];
  const float* Jt = (const float*)d_in[1];
  const float* wts = (const float*)d_in[2];
  const float* Rin = (const float*)d_in[3];
  const float* poseR = (const float*)d_in[4];
  const float* poseT = (const float*)d_in[5];
  const float* consts = (const float*)d_in[11];
  const float* c1w = (const float*)d_in[12];
  const float* c1b = (const float*)d_in[13];
  const float* c2w = (const float*)d_in[14];
  const float* c2b = (const float*)d_in[15];
  const float* f1w = (const float*)d_in[16];
  const float* f1b = (const float*)d_in[17];
  const float* f2w = (const float*)d_in[18];
  const float* f2b = (const float*)d_in[19];
  float* ws = (float*)d_ws;
  float* part = ws;                 // 3072
  float* h2 = part + 3072;          // 1,228,800 (NCHW f32)
  float* fcpart = h2 + 1228800;     // 1,228,800 ([b][sl][64])
  float* out = (float*)d_out;

  k_front<<<dim3(NJTRB + NCONVB), dim3(256), 0, stream>>>(Jt, wts, Rin, c1w, c1b,
                                                          c2w, c2b, part, h2);
  k_fc1_part<<<dim3(NSLICE), dim3(256), 0, stream>>>(h2, f1w, fcpart);
  k_final<<<dim3(64), dim3(256), 0, stream>>>(fcpart, f1b, f2w, f2b, consts, part,
                                              JtJ, poseR, poseT, out);
}

// Round 16
// 76.977 us; speedup vs baseline: 6.0732x; 6.0732x over previous
//
#include <hip/hip_runtime.h>
#include <math.h>

#define BATCH 64
#define WW 320
#define HWTOT 76800
#define HW4 19200
#define NJTRB 512       // jtr blocks, 8 per batch
#define JSL4 2400       // float4s per jtr block (contiguous)
#define NCONVB 768      // 64 b x 6 tiles x 2 ocg
#define KS 64
#define NSLICE 300

typedef _Float16 half2_t __attribute__((ext_vector_type(2)));
union U32H2 { unsigned int u; half2_t h; };
__device__ __forceinline__ unsigned int pack_h2(float a, float b) {
  U32H2 x; x.h = half2_t{(_Float16)a, (_Float16)b}; return x.u;
}
__device__ __forceinline__ half2_t u_as_h2(unsigned int u) { U32H2 x; x.u = u; return x.h; }

__device__ __forceinline__ float dot2acc(unsigned int a, unsigned int b, float c) {
  half2_t ah = u_as_h2(a), bh = u_as_h2(b);
  return c + (float)ah.x * (float)bh.x + (float)ah.y * (float)bh.y;
}

// LDS layout (bytes): sR f32[70][71] | sH1 uint4[34*35] | sW2 uint[288] | sW1 f32[72] | sB1 f32[8]
#define SR_F 0
#define SR_LD 71
#define SH1_U4 (70 * 71)            // float offset where uint4 array starts (16B aligned: 4970*4=19880, /16=1242.5 -> pad to 19888)
#define SH1_OFF_F 4972              // floats (19888 B, 16B aligned)
#define SW2_OFF_F (SH1_OFF_F + 34 * 35 * 4)   // uint4 = 4 floats each
#define SW1_OFF_F (SW2_OFF_F + 288)
#define SB1_OFF_F (SW1_OFF_F + 72)
#define SMEM_FLOATS (SB1_OFF_F + 8)  // 10132 floats = 40,528 B

// ================= K1: jtr partials + fused conv1+conv2 =================
__global__ __launch_bounds__(256) void k_front(
    const float* __restrict__ Jt, const float* __restrict__ wgt,
    const float* __restrict__ Rin, const float* __restrict__ c1w,
    const float* __restrict__ c1b, const float* __restrict__ c2w,
    const float* __restrict__ c2b, float* __restrict__ part,
    float* __restrict__ h2) {
  __shared__ __align__(16) float smem[SMEM_FLOATS];
  int tid = threadIdx.x;
  if (blockIdx.x < NJTRB) {
    // ---- jtr: verbatim R12 ----
    int b = blockIdx.x >> 3, s = blockIdx.x & 7;
    const float4* w4 = (const float4*)(wgt + (size_t)b * HWTOT);
    const float4* r4 = (const float4*)(Rin + (size_t)b * HWTOT);
    const float4* j4 = (const float4*)(Jt + (size_t)b * 6 * HWTOT);
    int base = s * JSL4;
    float acc[6] = {0.f, 0.f, 0.f, 0.f, 0.f, 0.f};
#pragma unroll 3
    for (int k = 0; k < 9; ++k) {
      int t = base + k * 256 + tid;
      float4 wv = w4[t], rv = r4[t];
      float4 p;
      p.x = wv.x * rv.x; p.y = wv.y * rv.y; p.z = wv.z * rv.z; p.w = wv.w * rv.w;
#pragma unroll
      for (int i = 0; i < 6; ++i) {
        float4 jv = j4[i * HW4 + t];
        acc[i] += jv.x * p.x + jv.y * p.y + jv.z * p.z + jv.w * p.w;
      }
    }
    if (tid < 96) {
      int t = base + 2304 + tid;
      float4 wv = w4[t], rv = r4[t];
      float4 p;
      p.x = wv.x * rv.x; p.y = wv.y * rv.y; p.z = wv.z * rv.z; p.w = wv.w * rv.w;
#pragma unroll
      for (int i = 0; i < 6; ++i) {
        float4 jv = j4[i * HW4 + t];
        acc[i] += jv.x * p.x + jv.y * p.y + jv.z * p.z + jv.w * p.w;
      }
    }
#pragma unroll
    for (int i = 0; i < 6; ++i) {
      float v = acc[i];
      for (int off = 32; off; off >>= 1) v += __shfl_down(v, off, 64);
      acc[i] = v;
    }
    float* sred = smem;
    int lane = tid & 63, wid = tid >> 6;
    if (lane == 0) {
#pragma unroll
      for (int i = 0; i < 6; ++i) sred[wid * 6 + i] = acc[i];
    }
    __syncthreads();
    if (tid < 6) {
      part[blockIdx.x * 6 + tid] =
          sred[0 + tid] + sred[6 + tid] + sred[12 + tid] + sred[18 + tid];
    }
    return;
  }
  // ---- fused conv block: (b, tile(ty,tx), ocg) ----
  int cb = blockIdx.x - NJTRB;
  int b = cb / 12, q = cb % 12;
  int tx = q % 3, ty = (q / 3) & 1, ocg = q / 6;
  int ty0 = 16 * ty, tx0 = 16 * tx;
  float* sR = smem + SR_F;                    // [70][71]
  uint4* sH1 = (uint4*)(smem + SH1_OFF_F);    // [34*35]
  unsigned int* sW2 = (unsigned int*)(smem + SW2_OFF_F);  // [72][4] for own ocg
  float* sW1 = smem + SW1_OFF_F;              // [tap][oc]
  float* sB1 = smem + SB1_OFF_F;
  if (tid < 72) sW1[tid] = c1w[(tid & 7) * 9 + (tid >> 3)];
  if (tid < 8) sB1[tid] = c1b[tid];
  // conv2 weight pack for own ocg: sW2[(tap*8+o)*4 + icp]
  if (tid < 72) {
    int tap = tid / 8, o = tid % 8;
    int oc = ocg * 8 + o;
#pragma unroll
    for (int icp = 0; icp < 4; ++icp) {
      float lo = c2w[oc * 72 + (2 * icp) * 9 + tap];
      float hi = c2w[oc * 72 + (2 * icp + 1) * 9 + tap];
      sW2[(tap * 8 + o) * 4 + icp] = pack_h2(lo, hi);
    }
  }
  // stage pooled-R tile: rows 64ty-3..+70, cols 64tx-3..+70 (zero-padded)
  int pr0 = 64 * ty - 3, pc0 = 64 * tx - 3;
  const float* src = Rin + (size_t)b * HWTOT;
  for (int idx = tid; idx < 70 * 70; idx += 256) {
    int r = idx / 70, c = idx % 70;
    int py = pr0 + r, px = pc0 + c;
    float v = 0.f;
    if (py >= 0 && py < 120 && px >= 0 && px < 160) {
      const float2* r0 = (const float2*)(src + (size_t)(2 * py) * WW);
      const float2* r1 = (const float2*)(src + (size_t)(2 * py + 1) * WW);
      float2 a = r0[px], bb = r1[px];
      v = fmaxf(fmaxf(a.x, a.y), fmaxf(bb.x, bb.y));
    }
    sR[r * SR_LD + c] = v;
  }
  __syncthreads();
  // conv1 (R12 compute pattern) -> packed f16 sH1, 34x34 cells (+1 col pad stride 35)
  for (int idx = tid; idx < 34 * 34; idx += 256) {
    int r = idx / 34, c = idx % 34;
    int hr = 32 * ty - 1 + r, hc = 32 * tx - 1 + c;
    float v[8] = {0.f, 0.f, 0.f, 0.f, 0.f, 0.f, 0.f, 0.f};
    if (hr >= 0 && hr < 60 && hc >= 0 && hc < 80) {
      float wnd[16];
#pragma unroll
      for (int i = 0; i < 4; ++i)
#pragma unroll
        for (int j = 0; j < 4; ++j) wnd[i * 4 + j] = sR[(2 * r + i) * SR_LD + (2 * c + j)];
      float pac[8][4];
#pragma unroll
      for (int o = 0; o < 8; ++o)
#pragma unroll
        for (int p = 0; p < 4; ++p) pac[o][p] = 0.f;
#pragma unroll
      for (int tap = 0; tap < 9; ++tap) {
        int ky = tap / 3, kx = tap % 3;
#pragma unroll
        for (int o = 0; o < 8; ++o) {
          float w = sW1[tap * 8 + o];
#pragma unroll
          for (int py = 0; py < 2; ++py)
#pragma unroll
            for (int px = 0; px < 2; ++px)
              pac[o][py * 2 + px] += w * wnd[(py + ky) * 4 + (px + kx)];
        }
      }
#pragma unroll
      for (int o = 0; o < 8; ++o) {
        float m = fmaxf(fmaxf(pac[o][0], pac[o][1]), fmaxf(pac[o][2], pac[o][3])) + sB1[o];
        v[o] = fmaxf(m, 0.f);
      }
    }
    uint4 st;
    st.x = pack_h2(v[0], v[1]);
    st.y = pack_h2(v[2], v[3]);
    st.z = pack_h2(v[4], v[5]);
    st.w = pack_h2(v[6], v[7]);
    sH1[r * 35 + c] = st;
  }
  __syncthreads();
  // conv2: verbatim R13 body, win from sH1, weights from sW2 (uniform broadcast)
  int ly = tid / 16, lx = tid % 16;
  uint4 win[16];
#pragma unroll
  for (int r = 0; r < 4; ++r)
#pragma unroll
    for (int c = 0; c < 4; ++c) win[r * 4 + c] = sH1[(2 * ly + r) * 35 + (2 * lx + c)];
  float acc[8][4];
#pragma unroll
  for (int o = 0; o < 8; ++o)
#pragma unroll
    for (int p = 0; p < 4; ++p) acc[o][p] = 0.f;
  const uint4* wq = (const uint4*)sW2;
#pragma unroll
  for (int tap = 0; tap < 9; ++tap) {
    int ky = tap / 3, kx = tap % 3;
#pragma unroll
    for (int o = 0; o < 8; ++o) {
      uint4 wv = wq[tap * 8 + o];
#pragma unroll
      for (int py = 0; py < 2; ++py)
#pragma unroll
        for (int px = 0; px < 2; ++px) {
          uint4 wn = win[(py + ky) * 4 + (px + kx)];
          float a = acc[o][py * 2 + px];
          a = dot2acc(wn.x, wv.x, a);
          a = dot2acc(wn.y, wv.y, a);
          a = dot2acc(wn.z, wv.z, a);
          a = dot2acc(wn.w, wv.w, a);
          acc[o][py * 2 + px] = a;
        }
    }
  }
  int y = ty0 + ly, x = tx0 + lx;
  if (y < 30 && x < 40) {
#pragma unroll
    for (int o = 0; o < 8; ++o) {
      int oc = ocg * 8 + o;
      float m = fmaxf(fmaxf(acc[o][0], acc[o][1]), fmaxf(acc[o][2], acc[o][3])) + c2b[oc];
      h2[(((size_t)b * 16 + oc) * 30 + y) * 40 + x] = fmaxf(m, 0.f);
    }
  }
}

// ================= K2: fc1 partial GEMM (verbatim R12) =================
__global__ __launch_bounds__(256) void k_fc1_part(
    const float* __restrict__ h2, const float* __restrict__ f1w,
    float* __restrict__ fcpart) {
  __shared__ __align__(16) float sH[KS * 68];
  __shared__ __align__(16) float sWt[KS * 68];
  int sl = blockIdx.x, k0 = sl * KS;
  int tid = threadIdx.x;
  for (int idx = tid; idx < 64 * KS; idx += 256) {
    int b = idx >> 6, kk = idx & 63;
    sH[kk * 68 + b] = h2[(size_t)b * 19200 + k0 + kk];
    sWt[kk * 68 + b] = f1w[(size_t)b * 19200 + k0 + kk];
  }
  __syncthreads();
  int bq = tid & 15, jq = tid >> 4;
  int b0 = bq * 4, j0 = jq * 4;
  float acc[4][4];
#pragma unroll
  for (int i = 0; i < 4; ++i)
#pragma unroll
    for (int j = 0; j < 4; ++j) acc[i][j] = 0.f;
  for (int kk = 0; kk < KS; ++kk) {
    float4 hv = *(const float4*)&sH[kk * 68 + b0];
    float4 wv = *(const float4*)&sWt[kk * 68 + j0];
    float hb[4] = {hv.x, hv.y, hv.z, hv.w};
    float wb[4] = {wv.x, wv.y, wv.z, wv.w};
#pragma unroll
    for (int i = 0; i < 4; ++i)
#pragma unroll
      for (int j = 0; j < 4; ++j) acc[i][j] += hb[i] * wb[j];
  }
#pragma unroll
  for (int i = 0; i < 4; ++i)
#pragma unroll
    for (int j = 0; j < 4; ++j)
      fcpart[(size_t)(b0 + i) * 19200 + sl * 64 + (j0 + j)] = acc[i][j];
}

// ================= K3: per-batch fc1-reduce + head + jtr-reduce + solve ================
__global__ __launch_bounds__(256) void k_final(
    const float* __restrict__ fcpart, const float* __restrict__ f1b,
    const float* __restrict__ f2w, const float* __restrict__ f2b,
    const float* __restrict__ consts, const float* __restrict__ part,
    const float* __restrict__ JtJ, const float* __restrict__ poseR,
    const float* __restrict__ poseT, float* __restrict__ out) {
  __shared__ __align__(16) float sred[16 * 64];
  __shared__ float fc1v[64];
  __shared__ float sf2w[384];
  __shared__ float sf2b[8];
  __shared__ float sconst[36];
  __shared__ float lg[6];
  __shared__ float lamv[6];
  __shared__ float jtrv[6];
  int b = blockIdx.x, tid = threadIdx.x;
  for (int i = tid; i < 384; i += 256) sf2w[i] = f2w[i];
  if (tid < 6) sf2b[tid] = f2b[tid];
  if (tid < 36) sconst[tid] = consts[tid];
  {
    const float4* fp4 = (const float4*)(fcpart + (size_t)b * 19200);
    int sg = tid >> 4, j4 = tid & 15;
    float4 a = make_float4(0.f, 0.f, 0.f, 0.f);
    for (int s = sg; s < NSLICE; s += 16) {
      float4 v = fp4[s * 16 + j4];
      a.x += v.x; a.y += v.y; a.z += v.z; a.w += v.w;
    }
    ((float4*)sred)[sg * 16 + j4] = a;
  }
  if (tid >= 64 && tid < 70) {
    int i = tid - 64;
    float v = 0.f;
    for (int s = 0; s < 8; ++s) v += part[(b * 8 + s) * 6 + i];
    jtrv[i] = v;
  }
  __syncthreads();
  if (tid < 64) {
    float v = 0.f;
#pragma unroll
    for (int sg = 0; sg < 16; ++sg) v += sred[sg * 64 + tid];
    fc1v[tid] = fmaxf(v + f1b[tid], 0.f);
  }
  __syncthreads();
  if (tid < 6) {
    float v = sf2b[tid];
#pragma unroll
    for (int k = 0; k < 64; ++k) v += fc1v[k] * sf2w[tid * 64 + k];
    lg[tid] = v;
  }
  __syncthreads();
  if (tid < 6) {
    float m = lg[0];
#pragma unroll
    for (int i = 1; i < 6; ++i) m = fmaxf(m, lg[i]);
    float e[6], ssum = 0.f;
#pragma unroll
    for (int i = 0; i < 6; ++i) { e[i] = expf(lg[i] - m); ssum += e[i]; }
    float inv = 1.f / ssum;
    float wc = 0.f;
#pragma unroll
    for (int i = 0; i < 6; ++i) wc += (e[i] * inv) * sconst[i * 6 + tid];
    float sg = 1.f / (1.f + expf(-wc));
    lamv[tid] = expf((-6.f + sg) * 2.302585092994046f);
  }
  __syncthreads();
  if (tid == 0) {
    float Hm[6][6];
    const float* srcH = JtJ + b * 36;
    float tr = 0.f;
#pragma unroll
    for (int i = 0; i < 6; ++i) {
#pragma unroll
      for (int jj = 0; jj < 6; ++jj) Hm[i][jj] = srcH[i * 6 + jj];
      tr += srcH[i * 6 + i];
    }
    float rhs[6];
#pragma unroll
    for (int i = 0; i < 6; ++i) {
      rhs[i] = jtrv[i];
      Hm[i][i] += lamv[i] + 1e-6f * tr + 1e-6f;
    }
    float L[6][6];
#pragma unroll
    for (int i = 0; i < 6; ++i) {
#pragma unroll
      for (int jj = 0; jj < 6; ++jj) {
        if (jj > i) continue;
        float s = Hm[i][jj];
#pragma unroll
        for (int k = 0; k < 6; ++k)
          if (k < jj) s -= L[i][k] * L[jj][k];
        if (i == jj) L[i][jj] = sqrtf(fmaxf(s, 1e-30f));
        else L[i][jj] = s / L[jj][jj];
      }
    }
    float yv[6];
#pragma unroll
    for (int i = 0; i < 6; ++i) {
      float s = rhs[i];
#pragma unroll
      for (int k = 0; k < 6; ++k)
        if (k < i) s -= L[i][k] * yv[k];
      yv[i] = s / L[i][i];
    }
    float xi[6];
#pragma unroll
    for (int ii = 5; ii >= 0; --ii) {
      float s = yv[ii];
#pragma unroll
      for (int k = 0; k < 6; ++k)
        if (k > ii) s -= L[k][ii] * xi[k];
      xi[ii] = s / L[ii][ii];
    }
    float wx = -xi[0], wy = -xi[1], wz = -xi[2];
    float th = fmaxf(sqrtf(wx * wx + wy * wy + wz * wz), 1e-12f);
    float ux = wx / th, uy = wy / th, uz = wz / th;
    float s = sinf(th), c1 = 1.f - cosf(th);
    float Rd[3][3];
    Rd[0][0] = 1.f + c1 * (ux * ux - 1.f);
    Rd[0][1] = -s * uz + c1 * (ux * uy);
    Rd[0][2] = s * uy + c1 * (ux * uz);
    Rd[1][0] = s * uz + c1 * (uy * ux);
    Rd[1][1] = 1.f + c1 * (uy * uy - 1.f);
    Rd[1][2] = -s * ux + c1 * (uy * uz);
    Rd[2][0] = -s * uy + c1 * (uz * ux);
    Rd[2][1] = s * ux + c1 * (uz * uy);
    Rd[2][2] = 1.f + c1 * (uz * uz - 1.f);
    float dt[3];
#pragma unroll
    for (int r = 0; r < 3; ++r)
      dt[r] = -(Rd[r][0] * xi[3] + Rd[r][1] * xi[4] + Rd[r][2] * xi[5]);
    const float* pR = poseR + b * 9;
    const float* pt = poseT + b * 3;
#pragma unroll
    for (int r = 0; r < 3; ++r) {
#pragma unroll
      for (int cc = 0; cc < 3; ++cc) {
        out[b * 12 + r * 4 + cc] =
            pR[r * 3 + 0] * Rd[0][cc] + pR[r * 3 + 1] * Rd[1][cc] + pR[r * 3 + 2] * Rd[2][cc];
      }
      out[b * 12 + r * 4 + 3] =
          pR[r * 3 + 0] * dt[0] + pR[r * 3 + 1] * dt[1] + pR[r * 3 + 2] * dt[2] + pt[r];
    }
  }
}

extern "C" void kernel_launch(void* const* d_in, const int* in_sizes, int n_in,
                              void* d_out, int out_size, void* d_ws, size_t ws_size,
                              hipStream_t stream) {
  const float* JtJ = (const float*)d_in[0];
  const float* Jt = (const float*)d_in[1];
  const float* wts = (const float*)d_in[2];
  const float* Rin = (const float*)d_in[3];
  const float* poseR = (const float*)d_in[4];
  const float* poseT = (const float*)d_in[5];
  const float* consts = (const float*)d_in[11];
  const float* c1w = (const float*)d_in[12];
  const float* c1b = (const float*)d_in[13];
  const float* c2w = (const float*)d_in[14];
  const float* c2b = (const float*)d_in[15];
  const float* f1w = (const float*)d_in[16];
  const float* f1b = (const float*)d_in[17];
  const float* f2w = (const float*)d_in[18];
  const float* f2b = (const float*)d_in[19];
  float* ws = (float*)d_ws;
  float* part = ws;                 // 3072
  float* h2 = part + 3072;          // 1,228,800 (NCHW f32)
  float* fcpart = h2 + 1228800;     // 1,228,800 ([b][sl][64])
  float* out = (float*)d_out;

  k_front<<<dim3(NJTRB + NCONVB), dim3(256), 0, stream>>>(Jt, wts, Rin, c1w, c1b,
                                                          c2w, c2b, part, h2);
  k_fc1_part<<<dim3(NSLICE), dim3(256), 0, stream>>>(h2, f1w, fcpart);
  k_final<<<dim3(64), dim3(256), 0, stream>>>(fcpart, f1b, f2w, f2b, consts, part,
                                              JtJ, poseR, poseT, out);
}

// Round 17
// 68.226 us; speedup vs baseline: 6.8522x; 1.1283x over previous
//
#include <hip/hip_runtime.h>
#include <math.h>

#define BATCH 64
#define WW 320
#define HWTOT 76800
#define HW4 19200
#define NJTRB 512       // jtr blocks per kernel, 8 per batch
#define JSL4 2400       // float4s per full slice; each kernel does half (1200)
#define KS 64
#define NSLICE 300

typedef _Float16 half2_t __attribute__((ext_vector_type(2)));
union U32H2 { unsigned int u; half2_t h; };
__device__ __forceinline__ unsigned int pack_h2(float a, float b) {
  U32H2 x; x.h = half2_t{(_Float16)a, (_Float16)b}; return x.u;
}
__device__ __forceinline__ half2_t u_as_h2(unsigned int u) { U32H2 x; x.u = u; return x.h; }

__device__ __forceinline__ float dot2acc(unsigned int a, unsigned int b, float c) {
  half2_t ah = u_as_h2(a), bh = u_as_h2(b);
  return c + (float)ah.x * (float)bh.x + (float)ah.y * (float)bh.y;
}

// ---- half-slice jtr: 1200 contiguous float4s (4 rounds + 176 tail), proven R5 body ----
__device__ __forceinline__ void jtr_half(
    const float* __restrict__ Jt, const float* __restrict__ wgt,
    const float* __restrict__ Rin, float* __restrict__ part,
    int b, int slot, int base, float* sred) {
  int tid = threadIdx.x;
  const float4* w4 = (const float4*)(wgt + (size_t)b * HWTOT);
  const float4* r4 = (const float4*)(Rin + (size_t)b * HWTOT);
  const float4* j4 = (const float4*)(Jt + (size_t)b * 6 * HWTOT);
  float acc[6] = {0.f, 0.f, 0.f, 0.f, 0.f, 0.f};
#pragma unroll 2
  for (int k = 0; k < 4; ++k) {
    int t = base + k * 256 + tid;
    float4 wv = w4[t], rv = r4[t];
    float4 p;
    p.x = wv.x * rv.x; p.y = wv.y * rv.y; p.z = wv.z * rv.z; p.w = wv.w * rv.w;
#pragma unroll
    for (int i = 0; i < 6; ++i) {
      float4 jv = j4[i * HW4 + t];
      acc[i] += jv.x * p.x + jv.y * p.y + jv.z * p.z + jv.w * p.w;
    }
  }
  if (tid < 176) {
    int t = base + 1024 + tid;
    float4 wv = w4[t], rv = r4[t];
    float4 p;
    p.x = wv.x * rv.x; p.y = wv.y * rv.y; p.z = wv.z * rv.z; p.w = wv.w * rv.w;
#pragma unroll
    for (int i = 0; i < 6; ++i) {
      float4 jv = j4[i * HW4 + t];
      acc[i] += jv.x * p.x + jv.y * p.y + jv.z * p.z + jv.w * p.w;
    }
  }
#pragma unroll
  for (int i = 0; i < 6; ++i) {
    float v = acc[i];
    for (int off = 32; off; off >>= 1) v += __shfl_down(v, off, 64);
    acc[i] = v;
  }
  int lane = tid & 63, wid = tid >> 6;
  if (lane == 0) {
#pragma unroll
    for (int i = 0; i < 6; ++i) sred[wid * 6 + i] = acc[i];
  }
  __syncthreads();
  if (tid < 6)
    part[slot * 6 + tid] = sred[tid] + sred[6 + tid] + sred[12 + tid] + sred[18 + tid];
}

// ================= K0: jtr half-A + conv1 (R12 body) -> h1u packed f16 NHWC ============
__global__ __launch_bounds__(256) void k_front1(
    const float* __restrict__ Jt, const float* __restrict__ wgt,
    const float* __restrict__ Rin, const float* __restrict__ c1w,
    const float* __restrict__ c1b, const float* __restrict__ c2w,
    float* __restrict__ part, unsigned int* __restrict__ h1u,
    unsigned int* __restrict__ wpk) {
  __shared__ float smem[34 * 37 + 96];
  int tid = threadIdx.x;
  if (blockIdx.x < NJTRB) {
    int b = blockIdx.x >> 3, s = blockIdx.x & 7;
    jtr_half(Jt, wgt, Rin, part, b, blockIdx.x, s * JSL4, smem);
    return;
  }
  int cb = blockIdx.x - NJTRB;
  int b = cb / 20, rem = cb % 20;
  int by = rem / 5, bx = rem % 5;
  if (cb == 0) {
    for (int i = tid; i < 576; i += 256) {
      int ocg = i / 288, tap = (i % 288) / 32, o = (i % 32) / 4, icp = i % 4;
      int oc = ocg * 8 + o;
      float lo = c2w[oc * 72 + (2 * icp) * 9 + tap];
      float hi = c2w[oc * 72 + (2 * icp + 1) * 9 + tap];
      wpk[i] = pack_h2(lo, hi);   // i == ocg*288 + tap*32 + o*4 + icp
    }
  }
  float (*sA)[37] = (float(*)[37])smem;
  float* sW = smem + 34 * 37;
  float* sB = sW + 72;
  if (tid < 72) sW[tid] = c1w[(tid & 7) * 9 + (tid >> 3)];
  if (tid < 8) sB[tid] = c1b[tid];
  int iy0 = 32 * by - 1;
  const float* src = Rin + (size_t)b * HWTOT;
  for (int idx = tid; idx < 34 * 18; idx += 256) {
    int pr = idx / 18, c4 = idx % 18;
    int py = iy0 + pr;
    int gx = 64 * bx - 4 + 4 * c4;
    float cell0 = 0.f, cell1 = 0.f;
    if (py >= 0 && py < 120 && gx >= 0 && gx < 320) {
      const float4* row0 = (const float4*)(src + (size_t)(2 * py) * WW + gx);
      const float4* row1 = (const float4*)(src + (size_t)(2 * py + 1) * WW + gx);
      float4 v0 = row0[0], v1 = row1[0];
      cell0 = fmaxf(fmaxf(v0.x, v0.y), fmaxf(v1.x, v1.y));
      cell1 = fmaxf(fmaxf(v0.z, v0.w), fmaxf(v1.z, v1.w));
    }
    sA[pr][2 * c4] = cell0;
    sA[pr][2 * c4 + 1] = cell1;
  }
  __syncthreads();
  int ly = tid / 16, lx = tid % 16;
  int y = 16 * by + ly, x = 16 * bx + lx;
  float win[16];
#pragma unroll
  for (int r = 0; r < 4; ++r)
#pragma unroll
    for (int c = 0; c < 4; ++c) win[r * 4 + c] = sA[2 * ly + r][2 * lx + c + 1];
  float acc[8][4];
#pragma unroll
  for (int oc = 0; oc < 8; ++oc)
#pragma unroll
    for (int p = 0; p < 4; ++p) acc[oc][p] = 0.f;
#pragma unroll
  for (int tap = 0; tap < 9; ++tap) {
    int ky = tap / 3, kx = tap % 3;
#pragma unroll
    for (int oc = 0; oc < 8; ++oc) {
      float wv = sW[tap * 8 + oc];
#pragma unroll
      for (int py = 0; py < 2; ++py)
#pragma unroll
        for (int px = 0; px < 2; ++px)
          acc[oc][py * 2 + px] += wv * win[(py + ky) * 4 + (px + kx)];
    }
  }
  if (y < 60) {
    float v[8];
#pragma unroll
    for (int oc = 0; oc < 8; ++oc)
      v[oc] = fmaxf(fmaxf(fmaxf(acc[oc][0], acc[oc][1]), fmaxf(acc[oc][2], acc[oc][3])) + sB[oc], 0.f);
    uint4 st;
    st.x = pack_h2(v[0], v[1]);
    st.y = pack_h2(v[2], v[3]);
    st.z = pack_h2(v[4], v[5]);
    st.w = pack_h2(v[6], v[7]);
    *(uint4*)(h1u + (((size_t)b * 60 + y) * 80 + x) * 4) = st;
  }
}

// ================= K1: jtr half-B + conv2 (R12 body) -> h2 f32 NCHW =====================
__global__ __launch_bounds__(256) void k_front2(
    const float* __restrict__ Jt, const float* __restrict__ wgt,
    const float* __restrict__ Rin, const unsigned int* __restrict__ h1u,
    const unsigned int* __restrict__ wpk, const float* __restrict__ c2b,
    float* __restrict__ part, float* __restrict__ h2) {
  __shared__ __align__(16) uint4 sA[34][36];   // 19,584 B
  int tid = threadIdx.x;
  if (blockIdx.x < NJTRB) {
    int b = blockIdx.x >> 3, s = blockIdx.x & 7;
    jtr_half(Jt, wgt, Rin, part, b, NJTRB + blockIdx.x, s * JSL4 + 1200, (float*)sA);
    return;
  }
  int cb = blockIdx.x - NJTRB;   // 0..767
  int b = cb / 12, r12 = cb % 12;
  int gx0 = r12 % 3, gy0 = (r12 / 3) % 2, ocg = r12 / 6;
  int ty0 = gy0 * 16, tx0 = gx0 * 16;
  int iy0 = ty0 * 2 - 1, ix0 = tx0 * 2 - 1;
  const unsigned int* src = h1u + (size_t)b * 60 * 80 * 4;
  for (int idx = tid; idx < 34 * 34; idx += 256) {
    int r = idx / 34, c = idx % 34;
    int gy = iy0 + r, gx = ix0 + c;
    uint4 v = make_uint4(0u, 0u, 0u, 0u);
    if (gy >= 0 && gy < 60 && gx >= 0 && gx < 80)
      v = *(const uint4*)(src + ((size_t)gy * 80 + gx) * 4);
    sA[r][c] = v;
  }
  __syncthreads();
  int ly = tid / 16, lx = tid % 16;
  uint4 win[16];
#pragma unroll
  for (int r = 0; r < 4; ++r)
#pragma unroll
    for (int c = 0; c < 4; ++c) win[r * 4 + c] = sA[2 * ly + r][2 * lx + c];
  float acc[8][4];
#pragma unroll
  for (int o = 0; o < 8; ++o)
#pragma unroll
    for (int p = 0; p < 4; ++p) acc[o][p] = 0.f;
  const uint4* wq = (const uint4*)wpk + ocg * 72;  // wave-uniform -> s_load
#pragma unroll
  for (int tap = 0; tap < 9; ++tap) {
    int ky = tap / 3, kx = tap % 3;
#pragma unroll
    for (int o = 0; o < 8; ++o) {
      uint4 wv = wq[tap * 8 + o];
#pragma unroll
      for (int py = 0; py < 2; ++py)
#pragma unroll
        for (int px = 0; px < 2; ++px) {
          uint4 wn = win[(py + ky) * 4 + (px + kx)];
          float a = acc[o][py * 2 + px];
          a = dot2acc(wn.x, wv.x, a);
          a = dot2acc(wn.y, wv.y, a);
          a = dot2acc(wn.z, wv.z, a);
          a = dot2acc(wn.w, wv.w, a);
          acc[o][py * 2 + px] = a;
        }
    }
  }
  int y = ty0 + ly, x = tx0 + lx;
  if (y < 30 && x < 40) {
#pragma unroll
    for (int o = 0; o < 8; ++o) {
      int oc = ocg * 8 + o;
      float m = fmaxf(fmaxf(acc[o][0], acc[o][1]), fmaxf(acc[o][2], acc[o][3])) + c2b[oc];
      h2[(((size_t)b * 16 + oc) * 30 + y) * 40 + x] = fmaxf(m, 0.f);
    }
  }
}

// ================= K2: fc1 partial GEMM (verbatim R12) =================
__global__ __launch_bounds__(256) void k_fc1_part(
    const float* __restrict__ h2, const float* __restrict__ f1w,
    float* __restrict__ fcpart) {
  __shared__ __align__(16) float sH[KS * 68];
  __shared__ __align__(16) float sWt[KS * 68];
  int sl = blockIdx.x, k0 = sl * KS;
  int tid = threadIdx.x;
  for (int idx = tid; idx < 64 * KS; idx += 256) {
    int b = idx >> 6, kk = idx & 63;
    sH[kk * 68 + b] = h2[(size_t)b * 19200 + k0 + kk];
    sWt[kk * 68 + b] = f1w[(size_t)b * 19200 + k0 + kk];
  }
  __syncthreads();
  int bq = tid & 15, jq = tid >> 4;
  int b0 = bq * 4, j0 = jq * 4;
  float acc[4][4];
#pragma unroll
  for (int i = 0; i < 4; ++i)
#pragma unroll
    for (int j = 0; j < 4; ++j) acc[i][j] = 0.f;
  for (int kk = 0; kk < KS; ++kk) {
    float4 hv = *(const float4*)&sH[kk * 68 + b0];
    float4 wv = *(const float4*)&sWt[kk * 68 + j0];
    float hb[4] = {hv.x, hv.y, hv.z, hv.w};
    float wb[4] = {wv.x, wv.y, wv.z, wv.w};
#pragma unroll
    for (int i = 0; i < 4; ++i)
#pragma unroll
      for (int j = 0; j < 4; ++j) acc[i][j] += hb[i] * wb[j];
  }
#pragma unroll
  for (int i = 0; i < 4; ++i)
#pragma unroll
    for (int j = 0; j < 4; ++j)
      fcpart[(size_t)(b0 + i) * 19200 + sl * 64 + (j0 + j)] = acc[i][j];
}

// ================= K3: per-batch fc1-reduce + head + jtr-reduce + solve ================
__global__ __launch_bounds__(256) void k_final(
    const float* __restrict__ fcpart, const float* __restrict__ f1b,
    const float* __restrict__ f2w, const float* __restrict__ f2b,
    const float* __restrict__ consts, const float* __restrict__ part,
    const float* __restrict__ JtJ, const float* __restrict__ poseR,
    const float* __restrict__ poseT, float* __restrict__ out) {
  __shared__ __align__(16) float sred[16 * 64];
  __shared__ float fc1v[64];
  __shared__ float sf2w[384];
  __shared__ float sf2b[8];
  __shared__ float sconst[36];
  __shared__ float lg[6];
  __shared__ float lamv[6];
  __shared__ float jtrv[6];
  int b = blockIdx.x, tid = threadIdx.x;
  for (int i = tid; i < 384; i += 256) sf2w[i] = f2w[i];
  if (tid < 6) sf2b[tid] = f2b[tid];
  if (tid < 36) sconst[tid] = consts[tid];
  {
    const float4* fp4 = (const float4*)(fcpart + (size_t)b * 19200);
    int sg = tid >> 4, j4 = tid & 15;
    float4 a = make_float4(0.f, 0.f, 0.f, 0.f);
    for (int s = sg; s < NSLICE; s += 16) {
      float4 v = fp4[s * 16 + j4];
      a.x += v.x; a.y += v.y; a.z += v.z; a.w += v.w;
    }
    ((float4*)sred)[sg * 16 + j4] = a;
  }
  if (tid >= 64 && tid < 70) {
    int i = tid - 64;
    float v = 0.f;
    for (int s = 0; s < 8; ++s)
      v += part[(b * 8 + s) * 6 + i] + part[(NJTRB + b * 8 + s) * 6 + i];
    jtrv[i] = v;
  }
  __syncthreads();
  if (tid < 64) {
    float v = 0.f;
#pragma unroll
    for (int sg = 0; sg < 16; ++sg) v += sred[sg * 64 + tid];
    fc1v[tid] = fmaxf(v + f1b[tid], 0.f);
  }
  __syncthreads();
  if (tid < 6) {
    float v = sf2b[tid];
#pragma unroll
    for (int k = 0; k < 64; ++k) v += fc1v[k] * sf2w[tid * 64 + k];
    lg[tid] = v;
  }
  __syncthreads();
  if (tid < 6) {
    float m = lg[0];
#pragma unroll
    for (int i = 1; i < 6; ++i) m = fmaxf(m, lg[i]);
    float e[6], ssum = 0.f;
#pragma unroll
    for (int i = 0; i < 6; ++i) { e[i] = expf(lg[i] - m); ssum += e[i]; }
    float inv = 1.f / ssum;
    float wc = 0.f;
#pragma unroll
    for (int i = 0; i < 6; ++i) wc += (e[i] * inv) * sconst[i * 6 + tid];
    float sg = 1.f / (1.f + expf(-wc));
    lamv[tid] = expf((-6.f + sg) * 2.302585092994046f);
  }
  __syncthreads();
  if (tid == 0) {
    float Hm[6][6];
    const float* srcH = JtJ + b * 36;
    float tr = 0.f;
#pragma unroll
    for (int i = 0; i < 6; ++i) {
#pragma unroll
      for (int jj = 0; jj < 6; ++jj) Hm[i][jj] = srcH[i * 6 + jj];
      tr += srcH[i * 6 + i];
    }
    float rhs[6];
#pragma unroll
    for (int i = 0; i < 6; ++i) {
      rhs[i] = jtrv[i];
      Hm[i][i] += lamv[i] + 1e-6f * tr + 1e-6f;
    }
    float L[6][6];
#pragma unroll
    for (int i = 0; i < 6; ++i) {
#pragma unroll
      for (int jj = 0; jj < 6; ++jj) {
        if (jj > i) continue;
        float s = Hm[i][jj];
#pragma unroll
        for (int k = 0; k < 6; ++k)
          if (k < jj) s -= L[i][k] * L[jj][k];
        if (i == jj) L[i][jj] = sqrtf(fmaxf(s, 1e-30f));
        else L[i][jj] = s / L[jj][jj];
      }
    }
    float yv[6];
#pragma unroll
    for (int i = 0; i < 6; ++i) {
      float s = rhs[i];
#pragma unroll
      for (int k = 0; k < 6; ++k)
        if (k < i) s -= L[i][k] * yv[k];
      yv[i] = s / L[i][i];
    }
    float xi[6];
#pragma unroll
    for (int ii = 5; ii >= 0; --ii) {
      float s = yv[ii];
#pragma unroll
      for (int k = 0; k < 6; ++k)
        if (k > ii) s -= L[k][ii] * xi[k];
      xi[ii] = s / L[ii][ii];
    }
    float wx = -xi[0], wy = -xi[1], wz = -xi[2];
    float th = fmaxf(sqrtf(wx * wx + wy * wy + wz * wz), 1e-12f);
    float ux = wx / th, uy = wy / th, uz = wz / th;
    float s = sinf(th), c1 = 1.f - cosf(th);
    float Rd[3][3];
    Rd[0][0] = 1.f + c1 * (ux * ux - 1.f);
    Rd[0][1] = -s * uz + c1 * (ux * uy);
    Rd[0][2] = s * uy + c1 * (ux * uz);
    Rd[1][0] = s * uz + c1 * (uy * ux);
    Rd[1][1] = 1.f + c1 * (uy * uy - 1.f);
    Rd[1][2] = -s * ux + c1 * (uy * uz);
    Rd[2][0] = -s * uy + c1 * (uz * ux);
    Rd[2][1] = s * ux + c1 * (uz * uy);
    Rd[2][2] = 1.f + c1 * (uz * uz - 1.f);
    float dt[3];
#pragma unroll
    for (int r = 0; r < 3; ++r)
      dt[r] = -(Rd[r][0] * xi[3] + Rd[r][1] * xi[4] + Rd[r][2] * xi[5]);
    const float* pR = poseR + b * 9;
    const float* pt = poseT + b * 3;
#pragma unroll
    for (int r = 0; r < 3; ++r) {
#pragma unroll
      for (int cc = 0; cc < 3; ++cc) {
        out[b * 12 + r * 4 + cc] =
            pR[r * 3 + 0] * Rd[0][cc] + pR[r * 3 + 1] * Rd[1][cc] + pR[r * 3 + 2] * Rd[2][cc];
      }
      out[b * 12 + r * 4 + 3] =
          pR[r * 3 + 0] * dt[0] + pR[r * 3 + 1] * dt[1] + pR[r * 3 + 2] * dt[2] + pt[r];
    }
  }
}

extern "C" void kernel_launch(void* const* d_in, const int* in_sizes, int n_in,
                              void* d_out, int out_size, void* d_ws, size_t ws_size,
                              hipStream_t stream) {
  const float* JtJ = (const float*)d_in[0];
  const float* Jt = (const float*)d_in[1];
  const float* wts = (const float*)d_in[2];
  const float* Rin = (const float*)d_in[3];
  const float* poseR = (const float*)d_in[4];
  const float* poseT = (const float*)d_in[5];
  const float* consts = (const float*)d_in[11];
  const float* c1w = (const float*)d_in[12];
  const float* c1b = (const float*)d_in[13];
  const float* c2w = (const float*)d_in[14];
  const float* c2b = (const float*)d_in[15];
  const float* f1w = (const float*)d_in[16];
  const float* f1b = (const float*)d_in[17];
  const float* f2w = (const float*)d_in[18];
  const float* f2b = (const float*)d_in[19];
  float* ws = (float*)d_ws;
  float* part = ws;                               // 1024*6 = 6144
  unsigned int* h1u = (unsigned int*)(ws + 6144); // 1,228,800 uints (packed f16 NHWC)
  float* h2 = ws + 6144 + 1228800;                // 1,228,800
  float* fcpart = h2 + 1228800;                   // 1,228,800 ([b][sl][64])
  unsigned int* wpk = (unsigned int*)(fcpart + 1228800);  // 576
  float* out = (float*)d_out;

  k_front1<<<dim3(NJTRB + 1280), dim3(256), 0, stream>>>(Jt, wts, Rin, c1w, c1b, c2w,
                                                         part, h1u, wpk);
  k_front2<<<dim3(NJTRB + 768), dim3(256), 0, stream>>>(Jt, wts, Rin, h1u, wpk, c2b,
                                                        part, h2);
  k_fc1_part<<<dim3(NSLICE), dim3(256), 0, stream>>>(h2, f1w, fcpart);
  k_final<<<dim3(64), dim3(256), 0, stream>>>(fcpart, f1b, f2w, f2b, consts, part,
                                              JtJ, poseR, poseT, out);
}

// Round 18
// 65.165 us; speedup vs baseline: 7.1741x; 1.0470x over previous
//
#include <hip/hip_runtime.h>
#include <math.h>

#define BATCH 64
#define WW 320
#define HWTOT 76800
#define HW4 19200
#define NJTRB 512       // jtr blocks, 8 per batch
#define JSL4 2400       // float4s per jtr block (contiguous)
#define NCONV1 1280
#define KS 64
#define NSLICE 300

typedef _Float16 half2_t __attribute__((ext_vector_type(2)));
union U32H2 { unsigned int u; half2_t h; };
__device__ __forceinline__ unsigned int pack_h2(float a, float b) {
  U32H2 x; x.h = half2_t{(_Float16)a, (_Float16)b}; return x.u;
}
__device__ __forceinline__ half2_t u_as_h2(unsigned int u) { U32H2 x; x.u = u; return x.h; }

__device__ __forceinline__ float dot2acc(unsigned int a, unsigned int b, float c) {
  half2_t ah = u_as_h2(a), bh = u_as_h2(b);
  return c + (float)ah.x * (float)bh.x + (float)ah.y * (float)bh.y;
}

// ================= K1: jtr partials + fused pool+conv1 (h1 -> packed f16 NHWC) ========
__global__ __launch_bounds__(256) void k_front(
    const float* __restrict__ Jt, const float* __restrict__ wgt,
    const float* __restrict__ Rin, const float* __restrict__ c1w,
    const float* __restrict__ c1b, const float* __restrict__ c2w,
    float* __restrict__ part, unsigned int* __restrict__ h1u,
    unsigned int* __restrict__ wpk) {
  __shared__ float smem[34 * 37 + 96];
  int tid = threadIdx.x;
  if (blockIdx.x < NJTRB) {
    int b = blockIdx.x >> 3, s = blockIdx.x & 7;
    const float4* w4 = (const float4*)(wgt + (size_t)b * HWTOT);
    const float4* r4 = (const float4*)(Rin + (size_t)b * HWTOT);
    const float4* j4 = (const float4*)(Jt + (size_t)b * 6 * HWTOT);
    int base = s * JSL4;
    float acc[6] = {0.f, 0.f, 0.f, 0.f, 0.f, 0.f};
#pragma unroll 3
    for (int k = 0; k < 9; ++k) {
      int t = base + k * 256 + tid;
      float4 wv = w4[t], rv = r4[t];
      float4 p;
      p.x = wv.x * rv.x; p.y = wv.y * rv.y; p.z = wv.z * rv.z; p.w = wv.w * rv.w;
#pragma unroll
      for (int i = 0; i < 6; ++i) {
        float4 jv = j4[i * HW4 + t];
        acc[i] += jv.x * p.x + jv.y * p.y + jv.z * p.z + jv.w * p.w;
      }
    }
    if (tid < 96) {
      int t = base + 2304 + tid;
      float4 wv = w4[t], rv = r4[t];
      float4 p;
      p.x = wv.x * rv.x; p.y = wv.y * rv.y; p.z = wv.z * rv.z; p.w = wv.w * rv.w;
#pragma unroll
      for (int i = 0; i < 6; ++i) {
        float4 jv = j4[i * HW4 + t];
        acc[i] += jv.x * p.x + jv.y * p.y + jv.z * p.z + jv.w * p.w;
      }
    }
#pragma unroll
    for (int i = 0; i < 6; ++i) {
      float v = acc[i];
      for (int off = 32; off; off >>= 1) v += __shfl_down(v, off, 64);
      acc[i] = v;
    }
    float* sred = smem;
    int lane = tid & 63, wid = tid >> 6;
    if (lane == 0) {
#pragma unroll
      for (int i = 0; i < 6; ++i) sred[wid * 6 + i] = acc[i];
    }
    __syncthreads();
    if (tid < 6) {
      part[blockIdx.x * 6 + tid] =
          sred[0 + tid] + sred[6 + tid] + sred[12 + tid] + sred[18 + tid];
    }
    return;
  }
  // ---- fused maxpool2(R) + conv1 + relu + maxpool2 -> h1 packed f16 NHWC ----
  int cb = blockIdx.x - NJTRB;
  int b = cb / 20, rem = cb % 20;
  int by = rem / 5, bx = rem % 5;
  // conv2 weight repack on block cb==0: wpk[ocg][tap][o][icp] (uint4-friendly order)
  if (cb == 0) {
    for (int i = tid; i < 576; i += 256) {
      int ocg = i / 288, tap = (i % 288) / 32, o = (i % 32) / 4, icp = i % 4;
      int oc = ocg * 8 + o;
      float lo = c2w[oc * 72 + (2 * icp) * 9 + tap];
      float hi = c2w[oc * 72 + (2 * icp + 1) * 9 + tap];
      wpk[i] = pack_h2(lo, hi);   // i == ocg*288 + tap*32 + o*4 + icp
    }
  }
  float (*sA)[37] = (float(*)[37])smem;
  float* sW = smem + 34 * 37;
  float* sB = sW + 72;
  if (tid < 72) sW[tid] = c1w[(tid & 7) * 9 + (tid >> 3)];
  if (tid < 8) sB[tid] = c1b[tid];
  int iy0 = 32 * by - 1;
  const float* src = Rin + (size_t)b * HWTOT;
  for (int idx = tid; idx < 34 * 18; idx += 256) {
    int pr = idx / 18, c4 = idx % 18;
    int py = iy0 + pr;
    int gx = 64 * bx - 4 + 4 * c4;
    float cell0 = 0.f, cell1 = 0.f;
    if (py >= 0 && py < 120 && gx >= 0 && gx < 320) {
      const float4* row0 = (const float4*)(src + (size_t)(2 * py) * WW + gx);
      const float4* row1 = (const float4*)(src + (size_t)(2 * py + 1) * WW + gx);
      float4 v0 = row0[0], v1 = row1[0];
      cell0 = fmaxf(fmaxf(v0.x, v0.y), fmaxf(v1.x, v1.y));
      cell1 = fmaxf(fmaxf(v0.z, v0.w), fmaxf(v1.z, v1.w));
    }
    sA[pr][2 * c4] = cell0;
    sA[pr][2 * c4 + 1] = cell1;
  }
  __syncthreads();
  int ly = tid / 16, lx = tid % 16;
  int y = 16 * by + ly, x = 16 * bx + lx;
  float win[16];
#pragma unroll
  for (int r = 0; r < 4; ++r)
#pragma unroll
    for (int c = 0; c < 4; ++c) win[r * 4 + c] = sA[2 * ly + r][2 * lx + c + 1];
  float acc[8][4];
#pragma unroll
  for (int oc = 0; oc < 8; ++oc)
#pragma unroll
    for (int p = 0; p < 4; ++p) acc[oc][p] = 0.f;
#pragma unroll
  for (int tap = 0; tap < 9; ++tap) {
    int ky = tap / 3, kx = tap % 3;
#pragma unroll
    for (int oc = 0; oc < 8; ++oc) {
      float wv = sW[tap * 8 + oc];
#pragma unroll
      for (int py = 0; py < 2; ++py)
#pragma unroll
        for (int px = 0; px < 2; ++px)
          acc[oc][py * 2 + px] += wv * win[(py + ky) * 4 + (px + kx)];
    }
  }
  if (y < 60) {
    float v[8];
#pragma unroll
    for (int oc = 0; oc < 8; ++oc)
      v[oc] = fmaxf(fmaxf(fmaxf(acc[oc][0], acc[oc][1]), fmaxf(acc[oc][2], acc[oc][3])) + sB[oc], 0.f);
    uint4 st;
    st.x = pack_h2(v[0], v[1]);
    st.y = pack_h2(v[2], v[3]);
    st.z = pack_h2(v[4], v[5]);
    st.w = pack_h2(v[6], v[7]);
    *(uint4*)(h1u + (((size_t)b * 60 + y) * 80 + x) * 4) = st;
  }
}

// ================= K2: conv2 f16 dot, icp-interleaved LDS, s_load weights =============
// grid (3,2,B*2), z = b*2 + ocg. h1u = packed f16 NHWC (uint4/cell = 4 ic-pairs).
__global__ __launch_bounds__(256) void k_conv2(
    const unsigned int* __restrict__ h1u, const unsigned int* __restrict__ wpk,
    const float* __restrict__ c2b, float* __restrict__ h2) {
  __shared__ __align__(16) uint4 sA[34][36];   // [row][col] = 4 ic-pair h2 values
  int b = blockIdx.z >> 1, ocg = blockIdx.z & 1;
  int ty0 = blockIdx.y * 16, tx0 = blockIdx.x * 16;
  int tid = threadIdx.x;
  int iy0 = ty0 * 2 - 1, ix0 = tx0 * 2 - 1;
  const unsigned int* src = h1u + (size_t)b * 60 * 80 * 4;
  for (int idx = tid; idx < 34 * 34; idx += 256) {
    int r = idx / 34, c = idx % 34;
    int gy = iy0 + r, gx = ix0 + c;
    uint4 v = make_uint4(0u, 0u, 0u, 0u);
    if (gy >= 0 && gy < 60 && gx >= 0 && gx < 80)
      v = *(const uint4*)(src + ((size_t)gy * 80 + gx) * 4);
    sA[r][c] = v;
  }
  __syncthreads();
  int ly = tid / 16, lx = tid % 16;
  // win[p] = uint4 of all 4 icp at that window cell — 16 ds_read_b128 total
  uint4 win[16];
#pragma unroll
  for (int r = 0; r < 4; ++r)
#pragma unroll
    for (int c = 0; c < 4; ++c) win[r * 4 + c] = sA[2 * ly + r][2 * lx + c];
  float acc[8][4];
#pragma unroll
  for (int o = 0; o < 8; ++o)
#pragma unroll
    for (int p = 0; p < 4; ++p) acc[o][p] = 0.f;
  // weights: wave-uniform uint4 loads (s_load_dwordx4), [tap][o] -> 4 icp pairs
  const uint4* wq = (const uint4*)wpk + ocg * 72;
#pragma unroll
  for (int tap = 0; tap < 9; ++tap) {
    int ky = tap / 3, kx = tap % 3;
#pragma unroll
    for (int o = 0; o < 8; ++o) {
      uint4 wv = wq[tap * 8 + o];   // .x..w = icp 0..3
#pragma unroll
      for (int py = 0; py < 2; ++py)
#pragma unroll
        for (int px = 0; px < 2; ++px) {
          uint4 wn = win[(py + ky) * 4 + (px + kx)];
          float a = acc[o][py * 2 + px];
          a = dot2acc(wn.x, wv.x, a);
          a = dot2acc(wn.y, wv.y, a);
          a = dot2acc(wn.z, wv.z, a);
          a = dot2acc(wn.w, wv.w, a);
          acc[o][py * 2 + px] = a;
        }
    }
  }
  int y = ty0 + ly, x = tx0 + lx;
  if (y < 30 && x < 40) {
#pragma unroll
    for (int o = 0; o < 8; ++o) {
      int oc = ocg * 8 + o;
      float m = fmaxf(fmaxf(acc[o][0], acc[o][1]), fmaxf(acc[o][2], acc[o][3])) + c2b[oc];
      h2[(((size_t)b * 16 + oc) * 30 + y) * 40 + x] = fmaxf(m, 0.f);
    }
  }
}

// ================= K3: fc1 partial GEMM, KS=64, 300 slices, transposed out =============
__global__ __launch_bounds__(256) void k_fc1_part(
    const float* __restrict__ h2, const float* __restrict__ f1w,
    float* __restrict__ fcpart) {
  __shared__ __align__(16) float sH[KS * 68];
  __shared__ __align__(16) float sWt[KS * 68];
  int sl = blockIdx.x, k0 = sl * KS;
  int tid = threadIdx.x;
  for (int idx = tid; idx < 64 * KS; idx += 256) {
    int b = idx >> 6, kk = idx & 63;
    sH[kk * 68 + b] = h2[(size_t)b * 19200 + k0 + kk];
    sWt[kk * 68 + b] = f1w[(size_t)b * 19200 + k0 + kk];
  }
  __syncthreads();
  int bq = tid & 15, jq = tid >> 4;
  int b0 = bq * 4, j0 = jq * 4;
  float acc[4][4];
#pragma unroll
  for (int i = 0; i < 4; ++i)
#pragma unroll
    for (int j = 0; j < 4; ++j) acc[i][j] = 0.f;
  for (int kk = 0; kk < KS; ++kk) {
    float4 hv = *(const float4*)&sH[kk * 68 + b0];
    float4 wv = *(const float4*)&sWt[kk * 68 + j0];
    float hb[4] = {hv.x, hv.y, hv.z, hv.w};
    float wb[4] = {wv.x, wv.y, wv.z, wv.w};
#pragma unroll
    for (int i = 0; i < 4; ++i)
#pragma unroll
      for (int j = 0; j < 4; ++j) acc[i][j] += hb[i] * wb[j];
  }
#pragma unroll
  for (int i = 0; i < 4; ++i)
#pragma unroll
    for (int j = 0; j < 4; ++j)
      fcpart[(size_t)(b0 + i) * 19200 + sl * 64 + (j0 + j)] = acc[i][j];
}

// ================= K4: per-batch fc1-reduce + head + jtr-reduce + solve ================
__global__ __launch_bounds__(256) void k_final(
    const float* __restrict__ fcpart, const float* __restrict__ f1b,
    const float* __restrict__ f2w, const float* __restrict__ f2b,
    const float* __restrict__ consts, const float* __restrict__ part,
    const float* __restrict__ JtJ, const float* __restrict__ poseR,
    const float* __restrict__ poseT, float* __restrict__ out) {
  __shared__ __align__(16) float sred[16 * 64];
  __shared__ float fc1v[64];
  __shared__ float sf2w[384];
  __shared__ float sf2b[8];
  __shared__ float sconst[36];
  __shared__ float lg[6];
  __shared__ float lamv[6];
  __shared__ float jtrv[6];
  int b = blockIdx.x, tid = threadIdx.x;
  for (int i = tid; i < 384; i += 256) sf2w[i] = f2w[i];
  if (tid < 6) sf2b[tid] = f2b[tid];
  if (tid < 36) sconst[tid] = consts[tid];
  {
    const float4* fp4 = (const float4*)(fcpart + (size_t)b * 19200);
    int sg = tid >> 4, j4 = tid & 15;
    float4 a = make_float4(0.f, 0.f, 0.f, 0.f);
    for (int s = sg; s < NSLICE; s += 16) {
      float4 v = fp4[s * 16 + j4];
      a.x += v.x; a.y += v.y; a.z += v.z; a.w += v.w;
    }
    ((float4*)sred)[sg * 16 + j4] = a;
  }
  if (tid >= 64 && tid < 70) {
    int i = tid - 64;
    float v = 0.f;
    for (int s = 0; s < 8; ++s) v += part[(b * 8 + s) * 6 + i];
    jtrv[i] = v;
  }
  __syncthreads();
  if (tid < 64) {
    float v = 0.f;
#pragma unroll
    for (int sg = 0; sg < 16; ++sg) v += sred[sg * 64 + tid];
    fc1v[tid] = fmaxf(v + f1b[tid], 0.f);
  }
  __syncthreads();
  if (tid < 6) {
    float v = sf2b[tid];
#pragma unroll
    for (int k = 0; k < 64; ++k) v += fc1v[k] * sf2w[tid * 64 + k];
    lg[tid] = v;
  }
  __syncthreads();
  if (tid < 6) {
    float m = lg[0];
#pragma unroll
    for (int i = 1; i < 6; ++i) m = fmaxf(m, lg[i]);
    float e[6], ssum = 0.f;
#pragma unroll
    for (int i = 0; i < 6; ++i) { e[i] = expf(lg[i] - m); ssum += e[i]; }
    float inv = 1.f / ssum;
    float wc = 0.f;
#pragma unroll
    for (int i = 0; i < 6; ++i) wc += (e[i] * inv) * sconst[i * 6 + tid];
    float sg = 1.f / (1.f + expf(-wc));
    lamv[tid] = expf((-6.f + sg) * 2.302585092994046f);
  }
  __syncthreads();
  if (tid == 0) {
    float Hm[6][6];
    const float* srcH = JtJ + b * 36;
    float tr = 0.f;
#pragma unroll
    for (int i = 0; i < 6; ++i) {
#pragma unroll
      for (int jj = 0; jj < 6; ++jj) Hm[i][jj] = srcH[i * 6 + jj];
      tr += srcH[i * 6 + i];
    }
    float rhs[6];
#pragma unroll
    for (int i = 0; i < 6; ++i) {
      rhs[i] = jtrv[i];
      Hm[i][i] += lamv[i] + 1e-6f * tr + 1e-6f;
    }
    float L[6][6];
#pragma unroll
    for (int i = 0; i < 6; ++i) {
#pragma unroll
      for (int jj = 0; jj < 6; ++jj) {
        if (jj > i) continue;
        float s = Hm[i][jj];
#pragma unroll
        for (int k = 0; k < 6; ++k)
          if (k < jj) s -= L[i][k] * L[jj][k];
        if (i == jj) L[i][jj] = sqrtf(fmaxf(s, 1e-30f));
        else L[i][jj] = s / L[jj][jj];
      }
    }
    float yv[6];
#pragma unroll
    for (int i = 0; i < 6; ++i) {
      float s = rhs[i];
#pragma unroll
      for (int k = 0; k < 6; ++k)
        if (k < i) s -= L[i][k] * yv[k];
      yv[i] = s / L[i][i];
    }
    float xi[6];
#pragma unroll
    for (int ii = 5; ii >= 0; --ii) {
      float s = yv[ii];
#pragma unroll
      for (int k = 0; k < 6; ++k)
        if (k > ii) s -= L[k][ii] * xi[k];
      xi[ii] = s / L[ii][ii];
    }
    float wx = -xi[0], wy = -xi[1], wz = -xi[2];
    float th = fmaxf(sqrtf(wx * wx + wy * wy + wz * wz), 1e-12f);
    float ux = wx / th, uy = wy / th, uz = wz / th;
    float s = sinf(th), c1 = 1.f - cosf(th);
    float Rd[3][3];
    Rd[0][0] = 1.f + c1 * (ux * ux - 1.f);
    Rd[0][1] = -s * uz + c1 * (ux * uy);
    Rd[0][2] = s * uy + c1 * (ux * uz);
    Rd[1][0] = s * uz + c1 * (uy * ux);
    Rd[1][1] = 1.f + c1 * (uy * uy - 1.f);
    Rd[1][2] = -s * ux + c1 * (uy * uz);
    Rd[2][0] = -s * uy + c1 * (uz * ux);
    Rd[2][1] = s * ux + c1 * (uz * uy);
    Rd[2][2] = 1.f + c1 * (uz * uz - 1.f);
    float dt[3];
#pragma unroll
    for (int r = 0; r < 3; ++r)
      dt[r] = -(Rd[r][0] * xi[3] + Rd[r][1] * xi[4] + Rd[r][2] * xi[5]);
    const float* pR = poseR + b * 9;
    const float* pt = poseT + b * 3;
#pragma unroll
    for (int r = 0; r < 3; ++r) {
#pragma unroll
      for (int cc = 0; cc < 3; ++cc) {
        out[b * 12 + r * 4 + cc] =
            pR[r * 3 + 0] * Rd[0][cc] + pR[r * 3 + 1] * Rd[1][cc] + pR[r * 3 + 2] * Rd[2][cc];
      }
      out[b * 12 + r * 4 + 3] =
          pR[r * 3 + 0] * dt[0] + pR[r * 3 + 1] * dt[1] + pR[r * 3 + 2] * dt[2] + pt[r];
    }
  }
}

extern "C" void kernel_launch(void* const* d_in, const int* in_sizes, int n_in,
                              void* d_out, int out_size, void* d_ws, size_t ws_size,
                              hipStream_t stream) {
  const float* JtJ = (const float*)d_in[0];
  const float* Jt = (const float*)d_in[1];
  const float* wts = (const float*)d_in[2];
  const float* Rin = (const float*)d_in[3];
  const float* poseR = (const float*)d_in[4];
  const float* poseT = (const float*)d_in[5];
  const float* consts = (const float*)d_in[11];
  const float* c1w = (const float*)d_in[12];
  const float* c1b = (const float*)d_in[13];
  const float* c2w = (const float*)d_in[14];
  const float* c2b = (const float*)d_in[15];
  const float* f1w = (const float*)d_in[16];
  const float* f1b = (const float*)d_in[17];
  const float* f2w = (const float*)d_in[18];
  const float* f2b = (const float*)d_in[19];
  float* ws = (float*)d_ws;
  float* part = ws;                               // 3072
  unsigned int* h1u = (unsigned int*)(ws + 3072); // 1,228,800 uints (packed f16 NHWC)
  float* h2 = ws + 3072 + 1228800;                // 1,228,800
  float* fcpart = h2 + 1228800;                   // 1,228,800 ([b][sl][64])
  unsigned int* wpk = (unsigned int*)(fcpart + 1228800);  // 576
  float* out = (float*)d_out;

  k_front<<<dim3(NJTRB + NCONV1), dim3(256), 0, stream>>>(Jt, wts, Rin, c1w, c1b, c2w,
                                                          part, h1u, wpk);
  k_conv2<<<dim3(3, 2, BATCH * 2), dim3(256), 0, stream>>>(h1u, wpk, c2b, h2);
  k_fc1_part<<<dim3(NSLICE), dim3(256), 0, stream>>>(h2, f1w, fcpart);
  k_final<<<dim3(64), dim3(256), 0, stream>>>(fcpart, f1b, f2w, f2b, consts, part,
                                              JtJ, poseR, poseT, out);
}